// Round 5
// baseline (560.611 us; speedup 1.0000x reference)
//
#include <hip/hip_runtime.h>
#include <math.h>

#define HID 64
#define BN_EPS 1e-5f
#define NBMAX 256

typedef unsigned int uint;
typedef unsigned short ushort;

// ============ radix-bucketed CSR build ============

__global__ __launch_bounds__(256) void k_bucket_hist(const int* __restrict__ ei, int E, int NB,
                                                     int* __restrict__ bcnt_d, int* __restrict__ bcnt_s) {
    __shared__ int hd[NBMAX], hs[NBMAX];
    int t = threadIdx.x;
    if (t < NB) { hd[t] = 0; hs[t] = 0; }
    __syncthreads();
    for (int e = blockIdx.x * 256 + t; e < E; e += gridDim.x * 256) {
        int src = ei[e], dst = ei[E + e];
        atomicAdd(&hs[src >> 8], 1);
        atomicAdd(&hd[dst >> 8], 1);
    }
    __syncthreads();
    if (t < NB) {
        if (hd[t]) atomicAdd(&bcnt_d[t], hd[t]);
        if (hs[t]) atomicAdd(&bcnt_s[t], hs[t]);
    }
}

__global__ __launch_bounds__(256) void k_bucket_scan(const int* __restrict__ bcnt_d, const int* __restrict__ bcnt_s,
                                                     int NB, int N, int E,
                                                     int* __restrict__ bbase_d, int* __restrict__ cursor_d,
                                                     int* __restrict__ bbase_s, int* __restrict__ cursor_s,
                                                     int* __restrict__ rowptr) {
    __shared__ int sh[256];
    int t = threadIdx.x;
    int v = (t < NB) ? bcnt_d[t] : 0;
    sh[t] = v; __syncthreads();
    for (int s = 1; s < 256; s <<= 1) { int u = (t >= s) ? sh[t - s] : 0; __syncthreads(); sh[t] += u; __syncthreads(); }
    int excl = sh[t] - v;
    if (t <= NB) bbase_d[t] = excl;
    if (t < NB) cursor_d[t] = excl;
    if (t == 0) rowptr[N] = E;
    __syncthreads();
    v = (t < NB) ? bcnt_s[t] : 0;
    sh[t] = v; __syncthreads();
    for (int s = 1; s < 256; s <<= 1) { int u = (t >= s) ? sh[t - s] : 0; __syncthreads(); sh[t] += u; __syncthreads(); }
    excl = sh[t] - v;
    if (t <= NB) bbase_s[t] = excl;
    if (t < NB) cursor_s[t] = excl;
}

__global__ __launch_bounds__(256) void k_scatter(const int* __restrict__ ei, int E, int NB,
                                                 int* __restrict__ cursor_d, int* __restrict__ cursor_s,
                                                 unsigned long long* __restrict__ bedge, int* __restrict__ bsrc) {
    __shared__ int hd[NBMAX], hs[NBMAX], curd[NBMAX], curs[NBMAX];
    int t = threadIdx.x;
    int chunk = (E + gridDim.x - 1) / gridDim.x;
    int e0 = blockIdx.x * chunk;
    int e1 = min(e0 + chunk, E);
    if (t < NB) { hd[t] = 0; hs[t] = 0; }
    __syncthreads();
    for (int e = e0 + t; e < e1; e += 256) {
        int src = ei[e], dst = ei[E + e];
        atomicAdd(&hd[dst >> 8], 1);
        atomicAdd(&hs[src >> 8], 1);
    }
    __syncthreads();
    if (t < NB) {
        curd[t] = hd[t] ? atomicAdd(&cursor_d[t], hd[t]) : 0;
        curs[t] = hs[t] ? atomicAdd(&cursor_s[t], hs[t]) : 0;
    }
    __syncthreads();
    for (int e = e0 + t; e < e1; e += 256) {
        int src = ei[e], dst = ei[E + e];
        int pd = atomicAdd(&curd[dst >> 8], 1);
        bedge[pd] = ((unsigned long long)(uint)dst << 32) | (uint)src;
        int ps = atomicAdd(&curs[src >> 8], 1);
        bsrc[ps] = src;
    }
}

__global__ __launch_bounds__(256) void k_build_csr(const unsigned long long* __restrict__ bedge,
                                                   const int* __restrict__ bbase_d, int N,
                                                   int* __restrict__ rowptr, int* __restrict__ eidx) {
    __shared__ int h[256], off[256], cur[256];
    int t = threadIdx.x, b = blockIdx.x;
    int base = bbase_d[b], end = bbase_d[b + 1];
    h[t] = 0; __syncthreads();
    for (int p = base + t; p < end; p += 256)
        atomicAdd(&h[(int)(bedge[p] >> 32) & 255], 1);
    __syncthreads();
    off[t] = h[t]; __syncthreads();
    for (int s = 1; s < 256; s <<= 1) { int u = (t >= s) ? off[t - s] : 0; __syncthreads(); off[t] += u; __syncthreads(); }
    int excl = off[t] - h[t];
    int node = (b << 8) + t;
    if (node <= N) rowptr[node] = base + excl;
    cur[t] = excl; __syncthreads();
    for (int p = base + t; p < end; p += 256) {
        unsigned long long be = bedge[p];
        int bin = (int)(be >> 32) & 255;
        int pos = atomicAdd(&cur[bin], 1);
        eidx[base + pos] = (int)(uint)(be & 0xffffffffULL);
    }
}

__global__ __launch_bounds__(256) void k_outdeg(const int* __restrict__ bsrc, const int* __restrict__ bbase_s,
                                                int N, float* __restrict__ dis) {
    __shared__ int h[256];
    int t = threadIdx.x, b = blockIdx.x;
    int base = bbase_s[b], end = bbase_s[b + 1];
    h[t] = 0; __syncthreads();
    for (int p = base + t; p < end; p += 256) atomicAdd(&h[bsrc[p] & 255], 1);
    __syncthreads();
    int node = (b << 8) + t;
    if (node < N) dis[node] = rsqrtf((float)(h[t] + 1));
}

// ============ BN stats ============

template <int F>
__global__ __launch_bounds__(256) void k_stats(const float* __restrict__ X, int n,
                                               float* __restrict__ stats) {
    const int RPB = 256 / F;
    int f = threadIdx.x & (F - 1);
    int rsub = threadIdx.x / F;
    float s = 0.f, q = 0.f;
    for (int r = blockIdx.x * RPB + rsub; r < n; r += gridDim.x * RPB) {
        float v = X[(size_t)r * F + f];
        s += v; q += v * v;
    }
    __shared__ float shs[256], shq[256];
    shs[threadIdx.x] = s; shq[threadIdx.x] = q;
    __syncthreads();
    if (threadIdx.x < F) {
        #pragma unroll
        for (int k = 1; k < RPB; k++) { s += shs[threadIdx.x + k * F]; q += shq[threadIdx.x + k * F]; }
        atomicAdd(&stats[f], s);
        atomicAdd(&stats[F + f], q);
    }
}

// ============ fold BN into linear ============

template <int K>
__global__ void k_fold(const float* __restrict__ stats, const float* __restrict__ gamma,
                       const float* __restrict__ beta, const float* __restrict__ W,
                       const float* __restrict__ bias, float n_inv,
                       float* __restrict__ Wout, float* __restrict__ bout, int has_bias) {
    int o = blockIdx.x;
    int f = threadIdx.x;
    float mu = stats[f] * n_inv;
    float var = stats[K + f] * n_inv - mu * mu;
    float a = gamma[f] * rsqrtf(var + BN_EPS);
    float w = W[(size_t)f * HID + o];
    Wout[(size_t)f * HID + o] = a * w;
    float contrib = (beta[f] - mu * a) * w;
    __shared__ float sh[K];
    sh[f] = contrib;
    __syncthreads();
    #pragma unroll
    for (int off = K / 2; off > 0; off >>= 1) {
        if (f < off) sh[f] += sh[f + off];
        __syncthreads();
    }
    if (f == 0) bout[o] = sh[0] + (has_bias ? bias[o] : 0.f);
}

// ============ GEMM: LDS-staged X (coalesced), wave K-split, W wave-uniform ============
// 256 threads = 4 waves; 64 rows/block. Wave w owns K-slice w (W addrs wave-uniform ->
// s_load broadcast). X tile (contiguous 64*K floats in global) staged coalesced into LDS
// at stride K+4 (16B-aligned, start-bank-group = r%8 -> balanced b128, no extra phases).
// Pairwise wave reduction through 2 publish buffers (stride 68) keeps LDS at 34.8KB ->
// 4 blocks/CU; __launch_bounds__(256,4) caps VGPR at 128 (4 waves/SIMD).

__device__ inline uint bf16pk(float a, float b) {
    uint ua = __builtin_bit_cast(uint, a);
    ua += 0x7fff + ((ua >> 16) & 1);
    uint ub = __builtin_bit_cast(uint, b);
    ub += 0x7fff + ((ub >> 16) & 1);
    return (ua >> 16) | (ub & 0xffff0000u);
}

template <int K, bool RELU, bool DIS>
__global__ __launch_bounds__(256, 4) void k_gemm(const float* __restrict__ X, const float* __restrict__ W,
                                                 const float* __restrict__ bias, const float* __restrict__ dis,
                                                 void* __restrict__ out, int n) {
    constexpr int R = 64;
    constexpr int KS = K / 4;            // 32 (K=128) or 16 (K=64)
    constexpr int STR = K + 4;           // 132 / 68: 16B-aligned rows, balanced bank groups
    constexpr int PSTR = 68;
    constexpr int PUB = R * PSTR;        // one publish buffer
    constexpr int LDSF = (R * STR > 2 * PUB) ? R * STR : 2 * PUB;
    __shared__ float lds[LDSF];

    int t = threadIdx.x;
    int w = t >> 6;                      // wave id = K-slice (wave-uniform)
    int r = t & 63;                      // row within block
    int row0 = blockIdx.x * R;
    int row = row0 + r;

    // ---- stage X tile: contiguous global region, perfectly coalesced ----
    {
        const float4* src = (const float4*)(X + (size_t)row0 * K);
        constexpr int T4 = R * K / 4;    // 2048 / 1024 float4s
        #pragma unroll
        for (int it = 0; it < T4 / 256; ++it) {
            int i = t + it * 256;
            int grow = i / (K / 4);
            int c4 = i % (K / 4);
            float4 v = make_float4(0.f, 0.f, 0.f, 0.f);
            if (row0 + grow < n) v = src[i];
            *(float4*)&lds[grow * STR + c4 * 4] = v;
        }
    }
    __syncthreads();

    // ---- compute: x from LDS, W wave-uniform from global ----
    float4 acc[16];
    #pragma unroll
    for (int j = 0; j < 16; j++) acc[j] = make_float4(0.f, 0.f, 0.f, 0.f);
    {
        float xr[KS];
        #pragma unroll
        for (int i = 0; i < KS / 4; i++)
            *(float4*)&xr[4 * i] = *(const float4*)&lds[r * STR + w * KS + 4 * i];
        const float* wbase = W + (size_t)w * KS * HID;     // wave-uniform
        #pragma unroll
        for (int kk = 0; kk < KS; kk++) {
            float xv = xr[kk];
            const float4* w4 = (const float4*)(wbase + (size_t)kk * HID);
            #pragma unroll
            for (int j = 0; j < 16; j++) {
                float4 ww = w4[j];
                acc[j].x = fmaf(xv, ww.x, acc[j].x);
                acc[j].y = fmaf(xv, ww.y, acc[j].y);
                acc[j].z = fmaf(xv, ww.z, acc[j].z);
                acc[j].w = fmaf(xv, ww.w, acc[j].w);
            }
        }
    }
    __syncthreads();   // everyone done reading X region before publish overwrites it

    // ---- pairwise reduction: (0+=2, 1+=3), then (0+=1) ----
    if (w >= 2) {
        float* dst = &lds[(w - 2) * PUB + r * PSTR];
        #pragma unroll
        for (int j = 0; j < 16; j++) *(float4*)&dst[4 * j] = acc[j];
    }
    __syncthreads();
    if (w < 2) {
        const float* srcp = &lds[w * PUB + r * PSTR];
        #pragma unroll
        for (int j = 0; j < 16; j++) {
            float4 p = *(const float4*)&srcp[4 * j];
            acc[j].x += p.x; acc[j].y += p.y; acc[j].z += p.z; acc[j].w += p.w;
        }
    }
    __syncthreads();
    if (w == 1) {
        float* dst = &lds[r * PSTR];
        #pragma unroll
        for (int j = 0; j < 16; j++) *(float4*)&dst[4 * j] = acc[j];
    }
    __syncthreads();
    if (w != 0 || row >= n) return;
    {
        const float* srcp = &lds[r * PSTR];
        #pragma unroll
        for (int j = 0; j < 16; j++) {
            float4 p = *(const float4*)&srcp[4 * j];
            acc[j].x += p.x; acc[j].y += p.y; acc[j].z += p.z; acc[j].w += p.w;
        }
    }

    const float4* b4 = (const float4*)bias;
    if constexpr (DIS) {
        float d = dis[row];
        uint4* o4 = (uint4*)((ushort*)out + (size_t)row * HID);
        #pragma unroll
        for (int h = 0; h < 8; h++) {
            float4 a = acc[2 * h], b = acc[2 * h + 1];
            float4 ba = b4[2 * h], bb = b4[2 * h + 1];
            uint4 pk;
            pk.x = bf16pk((a.x + ba.x) * d, (a.y + ba.y) * d);
            pk.y = bf16pk((a.z + ba.z) * d, (a.w + ba.w) * d);
            pk.z = bf16pk((b.x + bb.x) * d, (b.y + bb.y) * d);
            pk.w = bf16pk((b.z + bb.z) * d, (b.w + bb.w) * d);
            o4[h] = pk;
        }
    } else {
        float4* o4 = (float4*)((float*)out + (size_t)row * HID);
        #pragma unroll
        for (int j = 0; j < 16; j++) {
            float4 v = acc[j], bb = b4[j];
            v.x += bb.x; v.y += bb.y; v.z += bb.z; v.w += bb.w;
            if (RELU) { v.x = fmaxf(v.x, 0.f); v.y = fmaxf(v.y, 0.f); v.z = fmaxf(v.z, 0.f); v.w = fmaxf(v.w, 0.f); }
            o4[j] = v;
        }
    }
}

// ============ aggregation ============

__device__ inline float bfl(uint v) { return __builtin_bit_cast(float, v << 16); }
__device__ inline float bfh(uint v) { return __builtin_bit_cast(float, v & 0xffff0000u); }

__global__ __launch_bounds__(256) void k_agg(const ushort* __restrict__ s, const int* __restrict__ rowptr,
                                             const int* __restrict__ eidx, const float* __restrict__ dis,
                                             const float* __restrict__ bias, float* __restrict__ out, int n) {
    int wave = threadIdx.x >> 6;
    int lane = threadIdx.x & 63;
    int half = lane >> 5, li = lane & 31;
    int i = blockIdx.x * 8 + wave * 2 + half;
    if (i >= n) return;
    int f = li * 2;
    const uint* sp = (const uint*)s;
    uint v = sp[(size_t)i * 32 + li];
    float ax = bfl(v), ay = bfh(v);
    int q = rowptr[i], qe = rowptr[i + 1];
    for (; q + 4 <= qe; q += 4) {
        int j0 = eidx[q], j1 = eidx[q + 1], j2 = eidx[q + 2], j3 = eidx[q + 3];
        uint v0 = sp[(size_t)j0 * 32 + li];
        uint v1 = sp[(size_t)j1 * 32 + li];
        uint v2 = sp[(size_t)j2 * 32 + li];
        uint v3 = sp[(size_t)j3 * 32 + li];
        ax += (bfl(v0) + bfl(v1)) + (bfl(v2) + bfl(v3));
        ay += (bfh(v0) + bfh(v1)) + (bfh(v2) + bfh(v3));
    }
    for (; q < qe; ++q) {
        uint vv = sp[(size_t)eidx[q] * 32 + li];
        ax += bfl(vv); ay += bfh(vv);
    }
    float dd = dis[i];
    float2 r;
    r.x = fmaxf(fmaf(dd, ax, bias[f]), 0.f);
    r.y = fmaxf(fmaf(dd, ay, bias[f + 1]), 0.f);
    *(float2*)(out + (size_t)i * HID + f) = r;
}

// ============ global_add_pool ============

__global__ __launch_bounds__(256) void k_pool(const float* __restrict__ h, const int* __restrict__ batch,
                                              int n, float* __restrict__ out) {
    int g = blockIdx.x;
    int lo = 0, hi = n;
    while (lo < hi) { int mid = (lo + hi) >> 1; if (batch[mid] < g) lo = mid + 1; else hi = mid; }
    int start = lo;
    hi = n;
    while (lo < hi) { int mid = (lo + hi) >> 1; if (batch[mid] < g + 1) lo = mid + 1; else hi = mid; }
    int end = lo;
    int lane = threadIdx.x & 63;
    int rs = threadIdx.x >> 6;
    float acc = 0.f;
    for (int r = start + rs; r < end; r += 4) acc += h[(size_t)r * HID + lane];
    __shared__ float sh[256];
    sh[threadIdx.x] = acc;
    __syncthreads();
    if (threadIdx.x < 64) {
        acc = sh[threadIdx.x] + sh[64 + threadIdx.x] + sh[128 + threadIdx.x] + sh[192 + threadIdx.x];
        out[(size_t)g * HID + threadIdx.x] = acc;
    }
}

// ============ driver ============

extern "C" void kernel_launch(void* const* d_in, const int* in_sizes, int n_in,
                              void* d_out, int out_size, void* d_ws, size_t ws_size,
                              hipStream_t stream) {
    const float* x     = (const float*)d_in[0];
    const int*   ei    = (const int*)d_in[1];
    const int*   batch = (const int*)d_in[2];
    const float* bnfg  = (const float*)d_in[3];
    const float* bnfb  = (const float*)d_in[4];
    const float* Wfeat = (const float*)d_in[5];
    const float* bfeat = (const float*)d_in[6];
    const float* bng   = (const float*)d_in[7];
    const float* bnb   = (const float*)d_in[8];
    const float* Ws    = (const float*)d_in[9];
    const float* bs    = (const float*)d_in[10];
    float* out = (float*)d_out;

    const int N   = in_sizes[2];
    const int E   = in_sizes[1] / 2;
    const int FIN = in_sizes[0] / N;
    const int L   = in_sizes[9] / (HID * HID);
    const int G   = out_size / HID;
    const int NB  = (N + 255) >> 8;

    char* w = (char*)d_ws;
    auto alloc = [&](size_t bytes) { char* p = w; w += (bytes + 255) & ~(size_t)255; return p; };
    int*   bcnt_d = (int*)alloc(256 * 4);
    int*   bcnt_s = (int*)alloc(256 * 4);
    float* stats  = (float*)alloc(1024 * 4);
    size_t zero_bytes = (size_t)(w - (char*)d_ws);
    int*   bbase_d  = (int*)alloc(257 * 4);
    int*   cursor_d = (int*)alloc(256 * 4);
    int*   bbase_s  = (int*)alloc(257 * 4);
    int*   cursor_s = (int*)alloc(256 * 4);
    int*   rowptr   = (int*)alloc(((size_t)N + 1) * 4);
    int*   eidx     = (int*)alloc((size_t)E * 4);
    float* dis      = (float*)alloc((size_t)N * 4);
    float* Wf       = (float*)alloc((size_t)FIN * HID * 4);
    float* bf       = (float*)alloc(HID * 4);
    float* bufA     = (float*)alloc((size_t)N * HID * 4);
    ushort* bufB    = (ushort*)alloc((size_t)N * HID * 2);
    unsigned long long* bedge = (unsigned long long*)bufA;
    int* bsrc = (int*)bufB;

    hipMemsetAsync(d_ws, 0, zero_bytes, stream);

    int gG = (N + 63) / 64;   // 64 rows per gemm block

    // graph build
    k_bucket_hist<<<256, 256, 0, stream>>>(ei, E, NB, bcnt_d, bcnt_s);
    k_bucket_scan<<<1, 256, 0, stream>>>(bcnt_d, bcnt_s, NB, N, E,
                                         bbase_d, cursor_d, bbase_s, cursor_s, rowptr);
    k_scatter<<<256, 256, 0, stream>>>(ei, E, NB, cursor_d, cursor_s, bedge, bsrc);
    k_build_csr<<<NB, 256, 0, stream>>>(bedge, bbase_d, N, rowptr, eidx);
    k_outdeg<<<NB, 256, 0, stream>>>(bsrc, bbase_s, N, dis);

    // feature layer
    k_stats<128><<<256, 256, 0, stream>>>(x, N, stats);
    k_fold<128><<<HID, 128, 0, stream>>>(stats, bnfg, bnfb, Wfeat, bfeat, 1.f / (float)N, Wf, bf, 1);
    k_gemm<128, true, false><<<gG, 256, 0, stream>>>(x, Wf, bf, dis, bufA, N);

    // GCN layers
    for (int l = 0; l < L; ++l) {
        float* st = stats + 256 + 128 * l;
        k_stats<64><<<256, 256, 0, stream>>>(bufA, N, st);
        k_fold<64><<<HID, 64, 0, stream>>>(st, bng + (size_t)l * HID, bnb + (size_t)l * HID,
                                           Ws + (size_t)l * HID * HID, bf /*unused*/,
                                           1.f / (float)N, Wf, bf, 0);
        k_gemm<64, false, true><<<gG, 256, 0, stream>>>(bufA, Wf, bf, dis, (void*)bufB, N);
        k_agg<<<(N + 7) / 8, 256, 0, stream>>>(bufB, rowptr, eidx, dis, bs + (size_t)l * HID, bufA, N);
    }

    k_pool<<<G, 256, 0, stream>>>(bufA, batch, N, out);
}

// Round 6
// 373.404 us; speedup vs baseline: 1.5014x; 1.5014x over previous
//
#include <hip/hip_runtime.h>
#include <math.h>

#define HID 64
#define BN_EPS 1e-5f
#define NBMAX 256

typedef unsigned int uint;
typedef unsigned short ushort;

// ============ radix-bucketed CSR build ============

__global__ __launch_bounds__(256) void k_bucket_hist(const int* __restrict__ ei, int E, int NB,
                                                     int* __restrict__ bcnt_d, int* __restrict__ bcnt_s) {
    __shared__ int hd[NBMAX], hs[NBMAX];
    int t = threadIdx.x;
    if (t < NB) { hd[t] = 0; hs[t] = 0; }
    __syncthreads();
    for (int e = blockIdx.x * 256 + t; e < E; e += gridDim.x * 256) {
        int src = ei[e], dst = ei[E + e];
        atomicAdd(&hs[src >> 8], 1);
        atomicAdd(&hd[dst >> 8], 1);
    }
    __syncthreads();
    if (t < NB) {
        if (hd[t]) atomicAdd(&bcnt_d[t], hd[t]);
        if (hs[t]) atomicAdd(&bcnt_s[t], hs[t]);
    }
}

__global__ __launch_bounds__(256) void k_bucket_scan(const int* __restrict__ bcnt_d, const int* __restrict__ bcnt_s,
                                                     int NB, int N, int E,
                                                     int* __restrict__ bbase_d, int* __restrict__ cursor_d,
                                                     int* __restrict__ bbase_s, int* __restrict__ cursor_s,
                                                     int* __restrict__ rowptr) {
    __shared__ int sh[256];
    int t = threadIdx.x;
    int v = (t < NB) ? bcnt_d[t] : 0;
    sh[t] = v; __syncthreads();
    for (int s = 1; s < 256; s <<= 1) { int u = (t >= s) ? sh[t - s] : 0; __syncthreads(); sh[t] += u; __syncthreads(); }
    int excl = sh[t] - v;
    if (t <= NB) bbase_d[t] = excl;
    if (t < NB) cursor_d[t] = excl;
    if (t == 0) rowptr[N] = E;
    __syncthreads();
    v = (t < NB) ? bcnt_s[t] : 0;
    sh[t] = v; __syncthreads();
    for (int s = 1; s < 256; s <<= 1) { int u = (t >= s) ? sh[t - s] : 0; __syncthreads(); sh[t] += u; __syncthreads(); }
    excl = sh[t] - v;
    if (t <= NB) bbase_s[t] = excl;
    if (t < NB) cursor_s[t] = excl;
}

__global__ __launch_bounds__(256) void k_scatter(const int* __restrict__ ei, int E, int NB,
                                                 int* __restrict__ cursor_d, int* __restrict__ cursor_s,
                                                 unsigned long long* __restrict__ bedge, int* __restrict__ bsrc) {
    __shared__ int hd[NBMAX], hs[NBMAX], curd[NBMAX], curs[NBMAX];
    int t = threadIdx.x;
    int chunk = (E + gridDim.x - 1) / gridDim.x;
    int e0 = blockIdx.x * chunk;
    int e1 = min(e0 + chunk, E);
    if (t < NB) { hd[t] = 0; hs[t] = 0; }
    __syncthreads();
    for (int e = e0 + t; e < e1; e += 256) {
        int src = ei[e], dst = ei[E + e];
        atomicAdd(&hd[dst >> 8], 1);
        atomicAdd(&hs[src >> 8], 1);
    }
    __syncthreads();
    if (t < NB) {
        curd[t] = hd[t] ? atomicAdd(&cursor_d[t], hd[t]) : 0;
        curs[t] = hs[t] ? atomicAdd(&cursor_s[t], hs[t]) : 0;
    }
    __syncthreads();
    for (int e = e0 + t; e < e1; e += 256) {
        int src = ei[e], dst = ei[E + e];
        int pd = atomicAdd(&curd[dst >> 8], 1);
        bedge[pd] = ((unsigned long long)(uint)dst << 32) | (uint)src;
        int ps = atomicAdd(&curs[src >> 8], 1);
        bsrc[ps] = src;
    }
}

__global__ __launch_bounds__(256) void k_build_csr(const unsigned long long* __restrict__ bedge,
                                                   const int* __restrict__ bbase_d, int N,
                                                   int* __restrict__ rowptr, int* __restrict__ eidx) {
    __shared__ int h[256], off[256], cur[256];
    int t = threadIdx.x, b = blockIdx.x;
    int base = bbase_d[b], end = bbase_d[b + 1];
    h[t] = 0; __syncthreads();
    for (int p = base + t; p < end; p += 256)
        atomicAdd(&h[(int)(bedge[p] >> 32) & 255], 1);
    __syncthreads();
    off[t] = h[t]; __syncthreads();
    for (int s = 1; s < 256; s <<= 1) { int u = (t >= s) ? off[t - s] : 0; __syncthreads(); off[t] += u; __syncthreads(); }
    int excl = off[t] - h[t];
    int node = (b << 8) + t;
    if (node <= N) rowptr[node] = base + excl;
    cur[t] = excl; __syncthreads();
    for (int p = base + t; p < end; p += 256) {
        unsigned long long be = bedge[p];
        int bin = (int)(be >> 32) & 255;
        int pos = atomicAdd(&cur[bin], 1);
        eidx[base + pos] = (int)(uint)(be & 0xffffffffULL);
    }
}

__global__ __launch_bounds__(256) void k_outdeg(const int* __restrict__ bsrc, const int* __restrict__ bbase_s,
                                                int N, float* __restrict__ dis) {
    __shared__ int h[256];
    int t = threadIdx.x, b = blockIdx.x;
    int base = bbase_s[b], end = bbase_s[b + 1];
    h[t] = 0; __syncthreads();
    for (int p = base + t; p < end; p += 256) atomicAdd(&h[bsrc[p] & 255], 1);
    __syncthreads();
    int node = (b << 8) + t;
    if (node < N) dis[node] = rsqrtf((float)(h[t] + 1));
}

// ============ BN stats ============

template <int F>
__global__ __launch_bounds__(256) void k_stats(const float* __restrict__ X, int n,
                                               float* __restrict__ stats) {
    const int RPB = 256 / F;
    int f = threadIdx.x & (F - 1);
    int rsub = threadIdx.x / F;
    float s = 0.f, q = 0.f;
    for (int r = blockIdx.x * RPB + rsub; r < n; r += gridDim.x * RPB) {
        float v = X[(size_t)r * F + f];
        s += v; q += v * v;
    }
    __shared__ float shs[256], shq[256];
    shs[threadIdx.x] = s; shq[threadIdx.x] = q;
    __syncthreads();
    if (threadIdx.x < F) {
        #pragma unroll
        for (int k = 1; k < RPB; k++) { s += shs[threadIdx.x + k * F]; q += shq[threadIdx.x + k * F]; }
        atomicAdd(&stats[f], s);
        atomicAdd(&stats[F + f], q);
    }
}

// ============ fold BN into linear ============

template <int K>
__global__ void k_fold(const float* __restrict__ stats, const float* __restrict__ gamma,
                       const float* __restrict__ beta, const float* __restrict__ W,
                       const float* __restrict__ bias, float n_inv,
                       float* __restrict__ Wout, float* __restrict__ bout, int has_bias) {
    int o = blockIdx.x;
    int f = threadIdx.x;
    float mu = stats[f] * n_inv;
    float var = stats[K + f] * n_inv - mu * mu;
    float a = gamma[f] * rsqrtf(var + BN_EPS);
    float w = W[(size_t)f * HID + o];
    Wout[(size_t)f * HID + o] = a * w;
    float contrib = (beta[f] - mu * a) * w;
    __shared__ float sh[K];
    sh[f] = contrib;
    __syncthreads();
    #pragma unroll
    for (int off = K / 2; off > 0; off >>= 1) {
        if (f < off) sh[f] += sh[f + off];
        __syncthreads();
    }
    if (f == 0) bout[o] = sh[0] + (has_bias ? bias[o] : 0.f);
}

// ============ GEMM: classic 2D tile, 4x4 register tile per thread ============
// Block: 64 rows x 64 cols, 256 threads = 16 col-groups x 16 row-groups.
// Thread (tx,ty) owns rows 4ty..4ty+3, cols 4tx..4tx+3 -> 16 accumulators (no spill).
// Per KC=64 chunk: Xs[k][row] transposed (stride 68 -> aligned b128 reads, 4 broadcast
// addrs, conflict-free), Ws[k][col] direct coalesced copy. Inner loop per k:
// 2x ds_read_b128 + 16 FMA -> VALU-bound. LDS 33.8KB -> 4 blocks/CU.

__device__ inline uint bf16pk(float a, float b) {
    uint ua = __builtin_bit_cast(uint, a);
    ua += 0x7fff + ((ua >> 16) & 1);
    uint ub = __builtin_bit_cast(uint, b);
    ub += 0x7fff + ((ub >> 16) & 1);
    return (ua >> 16) | (ub & 0xffff0000u);
}

template <int K, bool RELU, bool DIS>
__global__ __launch_bounds__(256) void k_gemm(const float* __restrict__ X, const float* __restrict__ W,
                                              const float* __restrict__ bias, const float* __restrict__ dis,
                                              void* __restrict__ out, int n) {
    constexpr int MT = 64;           // rows per block
    constexpr int KC = 64;           // K chunk
    constexpr int XS = 68;           // Xs row-dim stride (16B-aligned, bank-spread)
    __shared__ float Xs[KC * XS];    // 17.4 KB, layout [k][row]
    __shared__ float Ws[KC * HID];   // 16.4 KB, layout [k][col]

    int t = threadIdx.x;
    int tx = t & 15;                 // col group: cols 4tx..4tx+3
    int ty = t >> 4;                 // row group: rows 4ty..4ty+3
    int row0 = blockIdx.x * MT;

    float acc[4][4];
    #pragma unroll
    for (int i = 0; i < 4; i++)
        #pragma unroll
        for (int j = 0; j < 4; j++) acc[i][j] = 0.f;

    for (int kc = 0; kc < K; kc += KC) {
        // stage X tile transposed: 64 rows x KC cols = 1024 float4, 4 per thread
        #pragma unroll
        for (int it = 0; it < 4; ++it) {
            int id = t + 256 * it;
            int r = id >> 4;            // 0..63
            int c4 = id & 15;           // 0..15 -> k-local 4*c4
            float4 v = make_float4(0.f, 0.f, 0.f, 0.f);
            if (row0 + r < n) v = *(const float4*)(X + (size_t)(row0 + r) * K + kc + 4 * c4);
            int kk = 4 * c4;
            Xs[(kk + 0) * XS + r] = v.x;
            Xs[(kk + 1) * XS + r] = v.y;
            Xs[(kk + 2) * XS + r] = v.z;
            Xs[(kk + 3) * XS + r] = v.w;
        }
        // stage W chunk: KC x 64 floats, contiguous in global
        {
            const float4* wsrc = (const float4*)(W + (size_t)kc * HID);
            #pragma unroll
            for (int it = 0; it < 4; ++it) {
                int id = t + 256 * it;
                ((float4*)Ws)[id] = wsrc[id];
            }
        }
        __syncthreads();

        #pragma unroll 8
        for (int k = 0; k < KC; ++k) {
            float4 xv = *(const float4*)&Xs[k * XS + 4 * ty];
            float4 wv = *(const float4*)&Ws[k * HID + 4 * tx];
            acc[0][0] = fmaf(xv.x, wv.x, acc[0][0]);
            acc[0][1] = fmaf(xv.x, wv.y, acc[0][1]);
            acc[0][2] = fmaf(xv.x, wv.z, acc[0][2]);
            acc[0][3] = fmaf(xv.x, wv.w, acc[0][3]);
            acc[1][0] = fmaf(xv.y, wv.x, acc[1][0]);
            acc[1][1] = fmaf(xv.y, wv.y, acc[1][1]);
            acc[1][2] = fmaf(xv.y, wv.z, acc[1][2]);
            acc[1][3] = fmaf(xv.y, wv.w, acc[1][3]);
            acc[2][0] = fmaf(xv.z, wv.x, acc[2][0]);
            acc[2][1] = fmaf(xv.z, wv.y, acc[2][1]);
            acc[2][2] = fmaf(xv.z, wv.z, acc[2][2]);
            acc[2][3] = fmaf(xv.z, wv.w, acc[2][3]);
            acc[3][0] = fmaf(xv.w, wv.x, acc[3][0]);
            acc[3][1] = fmaf(xv.w, wv.y, acc[3][1]);
            acc[3][2] = fmaf(xv.w, wv.z, acc[3][2]);
            acc[3][3] = fmaf(xv.w, wv.w, acc[3][3]);
        }
        __syncthreads();
    }

    // epilogue: thread stores 4 rows x 4 cols
    float4 bv = *(const float4*)(bias + 4 * tx);
    #pragma unroll
    for (int i = 0; i < 4; ++i) {
        int row = row0 + 4 * ty + i;
        if (row >= n) break;
        float vx = acc[i][0] + bv.x, vy = acc[i][1] + bv.y;
        float vz = acc[i][2] + bv.z, vw = acc[i][3] + bv.w;
        if constexpr (DIS) {
            float d = dis[row];
            uint2 pk;
            pk.x = bf16pk(vx * d, vy * d);
            pk.y = bf16pk(vz * d, vw * d);
            *(uint2*)((ushort*)out + (size_t)row * HID + 4 * tx) = pk;
        } else {
            float4 v;
            v.x = RELU ? fmaxf(vx, 0.f) : vx;
            v.y = RELU ? fmaxf(vy, 0.f) : vy;
            v.z = RELU ? fmaxf(vz, 0.f) : vz;
            v.w = RELU ? fmaxf(vw, 0.f) : vw;
            *(float4*)((float*)out + (size_t)row * HID + 4 * tx) = v;
        }
    }
}

// ============ aggregation ============

__device__ inline float bfl(uint v) { return __builtin_bit_cast(float, v << 16); }
__device__ inline float bfh(uint v) { return __builtin_bit_cast(float, v & 0xffff0000u); }

__global__ __launch_bounds__(256) void k_agg(const ushort* __restrict__ s, const int* __restrict__ rowptr,
                                             const int* __restrict__ eidx, const float* __restrict__ dis,
                                             const float* __restrict__ bias, float* __restrict__ out, int n) {
    int wave = threadIdx.x >> 6;
    int lane = threadIdx.x & 63;
    int half = lane >> 5, li = lane & 31;
    int i = blockIdx.x * 8 + wave * 2 + half;
    if (i >= n) return;
    int f = li * 2;
    const uint* sp = (const uint*)s;
    uint v = sp[(size_t)i * 32 + li];
    float ax = bfl(v), ay = bfh(v);
    int q = rowptr[i], qe = rowptr[i + 1];
    for (; q + 4 <= qe; q += 4) {
        int j0 = eidx[q], j1 = eidx[q + 1], j2 = eidx[q + 2], j3 = eidx[q + 3];
        uint v0 = sp[(size_t)j0 * 32 + li];
        uint v1 = sp[(size_t)j1 * 32 + li];
        uint v2 = sp[(size_t)j2 * 32 + li];
        uint v3 = sp[(size_t)j3 * 32 + li];
        ax += (bfl(v0) + bfl(v1)) + (bfl(v2) + bfl(v3));
        ay += (bfh(v0) + bfh(v1)) + (bfh(v2) + bfh(v3));
    }
    for (; q < qe; ++q) {
        uint vv = sp[(size_t)eidx[q] * 32 + li];
        ax += bfl(vv); ay += bfh(vv);
    }
    float dd = dis[i];
    float2 r;
    r.x = fmaxf(fmaf(dd, ax, bias[f]), 0.f);
    r.y = fmaxf(fmaf(dd, ay, bias[f + 1]), 0.f);
    *(float2*)(out + (size_t)i * HID + f) = r;
}

// ============ global_add_pool ============

__global__ __launch_bounds__(256) void k_pool(const float* __restrict__ h, const int* __restrict__ batch,
                                              int n, float* __restrict__ out) {
    int g = blockIdx.x;
    int lo = 0, hi = n;
    while (lo < hi) { int mid = (lo + hi) >> 1; if (batch[mid] < g) lo = mid + 1; else hi = mid; }
    int start = lo;
    hi = n;
    while (lo < hi) { int mid = (lo + hi) >> 1; if (batch[mid] < g + 1) lo = mid + 1; else hi = mid; }
    int end = lo;
    int lane = threadIdx.x & 63;
    int rs = threadIdx.x >> 6;
    float acc = 0.f;
    for (int r = start + rs; r < end; r += 4) acc += h[(size_t)r * HID + lane];
    __shared__ float sh[256];
    sh[threadIdx.x] = acc;
    __syncthreads();
    if (threadIdx.x < 64) {
        acc = sh[threadIdx.x] + sh[64 + threadIdx.x] + sh[128 + threadIdx.x] + sh[192 + threadIdx.x];
        out[(size_t)g * HID + threadIdx.x] = acc;
    }
}

// ============ driver ============

extern "C" void kernel_launch(void* const* d_in, const int* in_sizes, int n_in,
                              void* d_out, int out_size, void* d_ws, size_t ws_size,
                              hipStream_t stream) {
    const float* x     = (const float*)d_in[0];
    const int*   ei    = (const int*)d_in[1];
    const int*   batch = (const int*)d_in[2];
    const float* bnfg  = (const float*)d_in[3];
    const float* bnfb  = (const float*)d_in[4];
    const float* Wfeat = (const float*)d_in[5];
    const float* bfeat = (const float*)d_in[6];
    const float* bng   = (const float*)d_in[7];
    const float* bnb   = (const float*)d_in[8];
    const float* Ws    = (const float*)d_in[9];
    const float* bs    = (const float*)d_in[10];
    float* out = (float*)d_out;

    const int N   = in_sizes[2];
    const int E   = in_sizes[1] / 2;
    const int FIN = in_sizes[0] / N;
    const int L   = in_sizes[9] / (HID * HID);
    const int G   = out_size / HID;
    const int NB  = (N + 255) >> 8;

    char* w = (char*)d_ws;
    auto alloc = [&](size_t bytes) { char* p = w; w += (bytes + 255) & ~(size_t)255; return p; };
    int*   bcnt_d = (int*)alloc(256 * 4);
    int*   bcnt_s = (int*)alloc(256 * 4);
    float* stats  = (float*)alloc(1024 * 4);
    size_t zero_bytes = (size_t)(w - (char*)d_ws);
    int*   bbase_d  = (int*)alloc(257 * 4);
    int*   cursor_d = (int*)alloc(256 * 4);
    int*   bbase_s  = (int*)alloc(257 * 4);
    int*   cursor_s = (int*)alloc(256 * 4);
    int*   rowptr   = (int*)alloc(((size_t)N + 1) * 4);
    int*   eidx     = (int*)alloc((size_t)E * 4);
    float* dis      = (float*)alloc((size_t)N * 4);
    float* Wf       = (float*)alloc((size_t)FIN * HID * 4);
    float* bf       = (float*)alloc(HID * 4);
    float* bufA     = (float*)alloc((size_t)N * HID * 4);
    ushort* bufB    = (ushort*)alloc((size_t)N * HID * 2);
    unsigned long long* bedge = (unsigned long long*)bufA;
    int* bsrc = (int*)bufB;

    hipMemsetAsync(d_ws, 0, zero_bytes, stream);

    int gG = (N + 63) / 64;   // 64 rows per gemm block

    // graph build
    k_bucket_hist<<<256, 256, 0, stream>>>(ei, E, NB, bcnt_d, bcnt_s);
    k_bucket_scan<<<1, 256, 0, stream>>>(bcnt_d, bcnt_s, NB, N, E,
                                         bbase_d, cursor_d, bbase_s, cursor_s, rowptr);
    k_scatter<<<256, 256, 0, stream>>>(ei, E, NB, cursor_d, cursor_s, bedge, bsrc);
    k_build_csr<<<NB, 256, 0, stream>>>(bedge, bbase_d, N, rowptr, eidx);
    k_outdeg<<<NB, 256, 0, stream>>>(bsrc, bbase_s, N, dis);

    // feature layer
    k_stats<128><<<256, 256, 0, stream>>>(x, N, stats);
    k_fold<128><<<HID, 128, 0, stream>>>(stats, bnfg, bnfb, Wfeat, bfeat, 1.f / (float)N, Wf, bf, 1);
    k_gemm<128, true, false><<<gG, 256, 0, stream>>>(x, Wf, bf, dis, bufA, N);

    // GCN layers
    for (int l = 0; l < L; ++l) {
        float* st = stats + 256 + 128 * l;
        k_stats<64><<<256, 256, 0, stream>>>(bufA, N, st);
        k_fold<64><<<HID, 64, 0, stream>>>(st, bng + (size_t)l * HID, bnb + (size_t)l * HID,
                                           Ws + (size_t)l * HID * HID, bf /*unused*/,
                                           1.f / (float)N, Wf, bf, 0);
        k_gemm<64, false, true><<<gG, 256, 0, stream>>>(bufA, Wf, bf, dis, (void*)bufB, N);
        k_agg<<<(N + 7) / 8, 256, 0, stream>>>(bufB, rowptr, eidx, dis, bs + (size_t)l * HID, bufA, N);
    }

    k_pool<<<G, 256, 0, stream>>>(bufA, batch, N, out);
}